// Round 9
// baseline (409.079 us; speedup 1.0000x reference)
//
#include <hip/hip_runtime.h>
#include <hip/hip_bf16.h>

// ---------------------------------------------------------------------------
// GraphSAGE 3-layer, bf16 datapath, bucket-CSR.
// R9 changes vs R8:
//   (1) front roles INTERLEAVED (even blocks cast, odd blocks scatter):
//       R8 ran cast (BW-bound) then scatter (latency-bound) sequentially ->
//       front = sum of phases. Co-residency makes it ~max (m114 overlap).
//   (2) aggregation: full bucket index list preloaded in one coalesced read;
//       2 nodes per wave (n, n+M/2) -> 2 independent gather chains (2x MLP).
// ---------------------------------------------------------------------------

typedef __attribute__((ext_vector_type(8))) short bf16x8;   // 8 bf16 = 4 VGPR
typedef __attribute__((ext_vector_type(4))) float floatx4;

constexpr int M0 = 50000, M1 = 25000, M2 = 12500;
constexpr int NODE_OFF1 = 50000, NODE_OFF2 = 75000, M_TOT = 87500;
constexpr int NSRC = 100000;
constexpr int NPART = 8;
constexpr int CAP = 64;     // bucket capacity per node

__device__ inline unsigned short f2bf(float f) {
    union { float f; unsigned int u; } v{f};
    unsigned int u = v.u;
    return (unsigned short)((u + 0x7FFFu + ((u >> 16) & 1u)) >> 16);  // RNE
}
__device__ inline float bf2f(unsigned short h) {
    union { unsigned int u; float f; } v{(unsigned int)h << 16};
    return v.f;
}

// ---- fused front-end: cast | prep | scatter, role-interleaved -------------
constexpr int CAST_B = 25000;           // NSRC*256/4 / 256
constexpr int PREP_B = 640;

__global__ __launch_bounds__(256) void front_kernel(
    const float* __restrict__ x, unsigned short* __restrict__ xb,
    const float* __restrict__ Wn0, const float* __restrict__ Ws0,
    const float* __restrict__ Wn1, const float* __restrict__ Ws1,
    const float* __restrict__ Wn2, const float* __restrict__ Ws2,
    unsigned short* __restrict__ Wt0, unsigned short* __restrict__ Wt1,
    unsigned short* __restrict__ Wt2,
    const int* __restrict__ src0, const int* __restrict__ dst0,
    const int* __restrict__ src1, const int* __restrict__ dst1,
    const int* __restrict__ src2, const int* __restrict__ dst2,
    int* __restrict__ wptr, int* __restrict__ bkt,
    int E0, int E1, int E2, int SC_B)
{
    // role assignment: interleave cast (BW-bound) with scatter (latency-bound)
    const int b = blockIdx.x;
    const int minb = (CAST_B < SC_B) ? CAST_B : SC_B;
    const int inter = 2 * minb;
    int role, idx;
    if (b < inter) {
        role = b & 1;            // 0 = cast, 1 = scatter
        idx = b >> 1;
    } else {
        int r = b - inter;
        int scatRem = SC_B - minb;
        int castRem = CAST_B - minb;
        if (r < scatRem)                { role = 1; idx = minb + r; }
        else if (r < scatRem + castRem) { role = 0; idx = minb + (r - scatRem); }
        else                            { role = 2; idx = r - scatRem - castRem; }
    }

    if (role == 0) {
        long i = (long)idx * 256 + threadIdx.x;     // over NSRC*64 ushort4's
        float4 v = reinterpret_cast<const float4*>(x)[i];
        ushort4 o{f2bf(v.x), f2bf(v.y), f2bf(v.z), f2bf(v.w)};
        reinterpret_cast<ushort4*>(xb)[i] = o;
    } else if (role == 1) {
        // node-partitioned bucket scatter: idx&7 = node partition (contiguous
        // node range -> dense bkt store range), idx>>3 = edge slice.
        const int part = idx & (NPART - 1);
        const int i = (idx >> 3) * 256 + threadIdx.x;
        const int lo = (int)(((long)M_TOT * part) / NPART);
        const int hi = (int)(((long)M_TOT * (part + 1)) / NPART);
        int node, s;
        if (i < E0) {
            node = dst0[i]; s = src0[i];
        } else if (i < E0 + E1) {
            int j = i - E0; node = NODE_OFF1 + dst1[j]; s = src1[j];
        } else if (i < E0 + E1 + E2) {
            int j = i - E0 - E1; node = NODE_OFF2 + dst2[j]; s = src2[j];
        } else return;
        if (node >= lo && node < hi) {
            int p = atomicAdd(&wptr[node], 1);
            if (p < CAP) bkt[(size_t)node * CAP + p] = s;
        }
    } else {
        int bb = idx;
        const float* Wn; const float* Ws; unsigned short* Wt; int N; int base;
        if (bb < 256)      { Wn = Wn0; Ws = Ws0; Wt = Wt0; N = 256; base = 0; }
        else if (bb < 512) { Wn = Wn1; Ws = Ws1; Wt = Wt1; N = 256; base = 256; }
        else               { Wn = Wn2; Ws = Ws2; Wt = Wt2; N = 128; base = 512; }
        int idx2 = (bb - base) * 256 + threadIdx.x;   // over N*256, k fastest
        int n = idx2 >> 8, k = idx2 & 255;
        if (n >= N) return;
        Wt[(size_t)n * 512 + k]       = f2bf(Wn[(size_t)k * N + n]);
        Wt[(size_t)n * 512 + 256 + k] = f2bf(Ws[(size_t)k * N + n]);
    }
}

// ---- Aggregation: 1 wave per 2 nodes, bf16 rows (512B), fp32 accum --------
// Index lists preloaded whole (one coalesced 256B read, deg<=CAP=64);
// two interleaved gather chains per wave for 2x memory-level parallelism.

__global__ __launch_bounds__(256) void aggregate_mean_bf16(
    const unsigned short* __restrict__ h, const int* __restrict__ wptr,
    const int* __restrict__ bkt, unsigned short* __restrict__ mean, int M)
{
    int gid = blockIdx.x * 256 + threadIdx.x;
    int w = gid >> 6;
    int lane = gid & 63;
    int half = (M + 1) >> 1;
    if (w >= half) return;
    int n0 = w, n1 = w + half;
    bool has1 = (n1 < M);
    int c0 = min(wptr[n0], CAP);
    int c1 = has1 ? min(wptr[n1], CAP) : 0;
    int sidx0 = bkt[(size_t)n0 * CAP + lane];                 // full list, 1 read
    int sidx1 = has1 ? bkt[(size_t)n1 * CAP + lane] : 0;
    float a0x = 0.f, a0y = 0.f, a0z = 0.f, a0w = 0.f;
    float a1x = 0.f, a1y = 0.f, a1z = 0.f, a1w = 0.f;
    int mx = max(c0, c1);
    for (int j = 0; j < mx; ++j) {
        if (j < c0) {                                 // wave-uniform branch
            int s = __shfl(sidx0, j);
            ushort4 v = *(const ushort4*)(h + (size_t)s * 256 + lane * 4);
            a0x += bf2f(v.x); a0y += bf2f(v.y); a0z += bf2f(v.z); a0w += bf2f(v.w);
        }
        if (j < c1) {
            int s = __shfl(sidx1, j);
            ushort4 v = *(const ushort4*)(h + (size_t)s * 256 + lane * 4);
            a1x += bf2f(v.x); a1y += bf2f(v.y); a1z += bf2f(v.z); a1w += bf2f(v.w);
        }
    }
    float i0 = 1.0f / (float)max(c0, 1);
    ushort4 o0{f2bf(a0x * i0), f2bf(a0y * i0), f2bf(a0z * i0), f2bf(a0w * i0)};
    *(ushort4*)(mean + (size_t)n0 * 256 + lane * 4) = o0;
    if (has1) {
        float i1 = 1.0f / (float)max(c1, 1);
        ushort4 o1{f2bf(a1x * i1), f2bf(a1y * i1), f2bf(a1z * i1), f2bf(a1w * i1)};
        *(ushort4*)(mean + (size_t)n1 * 256 + lane * 4) = o1;
    }
}

// ---- Fused-K MFMA GEMM ----------------------------------------------------
// C[m][n] = sum_{k<512} Acat[m][k] * Wt[n][k],  Acat = [mean | h] (K-concat).
// 128x128 block tile, BK=64, 4 waves, 64x64/wave as 4x4 mfma_f32_16x16x32_bf16.

template <int RELU, int OUT_BF16>
__global__ __launch_bounds__(256) void sage_mfma(
    const unsigned short* __restrict__ A1,  // mean  [>=ceil128(M)][256]
    const unsigned short* __restrict__ A2,  // hsrc  [>=ceil128(M)][256]
    const unsigned short* __restrict__ Wt,  // [N][512]
    const float* __restrict__ bias,
    void* __restrict__ out, int M, int N)
{
    constexpr int PK = 64 + 8;  // LDS row pitch in bf16 (144 B)
    __shared__ unsigned short sA[128][PK];
    __shared__ unsigned short sB[128][PK];

    const int tid = threadIdx.x;
    const int bm = blockIdx.y * 128;
    const int bn = blockIdx.x * 128;
    const int wid = tid >> 6, lane = tid & 63;
    const int wm = (wid >> 1) * 64;
    const int wn = (wid & 1) * 64;
    const int quad = lane >> 4, l16 = lane & 15;

    const int sr = tid >> 1;
    const int sc = (tid & 1) * 32;

    floatx4 acc[4][4] = {};

    for (int k0 = 0; k0 < 512; k0 += 64) {
        const unsigned short* Ab = (k0 < 256) ? A1 : A2;
        const int ak = k0 & 255;
        const float4* ag = (const float4*)(Ab + (size_t)(bm + sr) * 256 + ak + sc);
        float4 a0 = ag[0], a1 = ag[1], a2 = ag[2], a3 = ag[3];
        const float4* bg = (const float4*)(Wt + (size_t)(bn + sr) * 512 + k0 + sc);
        float4 b0 = bg[0], b1 = bg[1], b2 = bg[2], b3 = bg[3];
        __syncthreads();
        *(float4*)&sA[sr][sc]      = a0;
        *(float4*)&sA[sr][sc + 8]  = a1;
        *(float4*)&sA[sr][sc + 16] = a2;
        *(float4*)&sA[sr][sc + 24] = a3;
        *(float4*)&sB[sr][sc]      = b0;
        *(float4*)&sB[sr][sc + 8]  = b1;
        *(float4*)&sB[sr][sc + 16] = b2;
        *(float4*)&sB[sr][sc + 24] = b3;
        __syncthreads();
#pragma unroll
        for (int ks = 0; ks < 64; ks += 32) {
            bf16x8 af[4], bfr[4];
#pragma unroll
            for (int i = 0; i < 4; ++i)
                af[i] = *(const bf16x8*)&sA[wm + i * 16 + l16][ks + quad * 8];
#pragma unroll
            for (int j = 0; j < 4; ++j)
                bfr[j] = *(const bf16x8*)&sB[wn + j * 16 + l16][ks + quad * 8];
#pragma unroll
            for (int i = 0; i < 4; ++i)
#pragma unroll
                for (int j = 0; j < 4; ++j)
                    acc[i][j] = __builtin_amdgcn_mfma_f32_16x16x32_bf16(
                        af[i], bfr[j], acc[i][j], 0, 0, 0);
        }
    }

    // epilogue: C row = quad*4 + reg, col = l16 (verified m89/m91)
#pragma unroll
    for (int j = 0; j < 4; ++j) {
        int col = bn + wn + j * 16 + l16;
        float bcol = bias[col];
#pragma unroll
        for (int i = 0; i < 4; ++i) {
#pragma unroll
            for (int r = 0; r < 4; ++r) {
                int row = bm + wm + i * 16 + quad * 4 + r;
                if (row < M) {
                    float v = acc[i][j][r] + bcol;
                    if (RELU) v = fmaxf(v, 0.0f);
                    if (OUT_BF16)
                        ((unsigned short*)out)[(size_t)row * N + col] = f2bf(v);
                    else
                        ((float*)out)[(size_t)row * N + col] = v;
                }
            }
        }
    }
}

// ---------------------------------------------------------------------------

extern "C" void kernel_launch(void* const* d_in, const int* in_sizes, int n_in,
                              void* d_out, int out_size, void* d_ws, size_t ws_size,
                              hipStream_t stream)
{
    const float* x   = (const float*)d_in[0];
    const float* Wn0 = (const float*)d_in[1];
    const float* Ws0 = (const float*)d_in[2];
    const float* b0  = (const float*)d_in[3];
    const float* Wn1 = (const float*)d_in[4];
    const float* Ws1 = (const float*)d_in[5];
    const float* b1  = (const float*)d_in[6];
    const float* Wn2 = (const float*)d_in[7];
    const float* Ws2 = (const float*)d_in[8];
    const float* b2  = (const float*)d_in[9];
    const int* src0 = (const int*)d_in[10];
    const int* dst0 = (const int*)d_in[11];
    const int* src1 = (const int*)d_in[12];
    const int* dst1 = (const int*)d_in[13];
    const int* src2 = (const int*)d_in[14];
    const int* dst2 = (const int*)d_in[15];
    const int E0 = in_sizes[10], E1 = in_sizes[12], E2 = in_sizes[14];
    const int E_tot = E0 + E1 + E2;

    // --- workspace layout ---
    unsigned short* xb   = (unsigned short*)d_ws;             // [100000][256]
    unsigned short* mean = xb   + (size_t)NSRC  * 256;        // [50048][256]
    unsigned short* h0   = mean + (size_t)50048 * 256;        // [50048][256]
    unsigned short* h1   = h0   + (size_t)50048 * 256;        // [25088][256]
    unsigned short* Wt0  = h1   + (size_t)25088 * 256;        // [256][512]
    unsigned short* Wt1  = Wt0  + 256 * 512;
    unsigned short* Wt2  = Wt1  + 256 * 512;                  // [128][512]
    int* wptr   = (int*)(Wt2 + 128 * 512);                    // [87500]
    int* bkt    = wptr + M_TOT;                               // [87500*64]
    float* outp = (float*)d_out;

    // wptr must be zero before scatter atomics (stream-ordered).
    hipMemsetAsync(wptr, 0, (size_t)M_TOT * sizeof(int), stream);

    const int sc_b = (E_tot + 255) / 256;
    const int SC_B = NPART * sc_b;
    front_kernel<<<dim3(CAST_B + PREP_B + SC_B), dim3(256), 0, stream>>>(
        x, xb, Wn0, Ws0, Wn1, Ws1, Wn2, Ws2, Wt0, Wt1, Wt2,
        src0, dst0, src1, dst1, src2, dst2, wptr, bkt, E0, E1, E2, SC_B);

    auto run_layer = [&](const unsigned short* hin, int node_off, int M,
                         const unsigned short* Wt, const float* b,
                         void* hout, int N, bool relu, bool out_bf16) {
        int halfw = (M + 1) >> 1;
        aggregate_mean_bf16<<<dim3((halfw * 64 + 255) / 256), dim3(256), 0, stream>>>(
            hin, wptr + node_off, bkt + (size_t)node_off * CAP, mean, M);
        dim3 g(N / 128, (M + 127) / 128);
        if (out_bf16)
            sage_mfma<1, 1><<<g, dim3(256), 0, stream>>>(mean, hin, Wt, b, hout, M, N);
        else
            sage_mfma<0, 0><<<g, dim3(256), 0, stream>>>(mean, hin, Wt, b, hout, M, N);
    };

    run_layer(xb, 0,         M0, Wt0, b0, h0,   256, true,  true);
    run_layer(h0, NODE_OFF1, M1, Wt1, b1, h1,   256, true,  true);
    run_layer(h1, NODE_OFF2, M2, Wt2, b2, outp, 128, false, false);
}